// Round 1
// baseline (1674.122 us; speedup 1.0000x reference)
//
#include <hip/hip_runtime.h>

#define TT 512
#define BB 32
#define KK 15

typedef __attribute__((ext_vector_type(8))) short short8;
typedef __attribute__((ext_vector_type(4))) float f32x4;
typedef __attribute__((ext_vector_type(8))) unsigned short us8;
typedef __attribute__((ext_vector_type(4))) unsigned short us4;

__device__ __forceinline__ float bf2f(unsigned short u){
  union { unsigned int i; float f; } v; v.i = ((unsigned int)u) << 16; return v.f;
}
__device__ __forceinline__ unsigned short f2bf(float f){
  union { float f; unsigned int i; } v; v.f = f;
  return (unsigned short)((v.i + 0x7fffu + ((v.i >> 16) & 1u)) >> 16);
}
// raw barrier: does NOT drain vmcnt (keeps global prefetch in flight across steps)
__device__ __forceinline__ void block_sync(){
  asm volatile("s_waitcnt lgkmcnt(0)" ::: "memory");
  __builtin_amdgcn_s_barrier();
  asm volatile("" ::: "memory");
}

// ---------- prep: f32 -> bf16 weights, fused bias ----------
__global__ void k_prep(const float* __restrict__ wih, const float* __restrict__ whh,
                       const float* __restrict__ bih, const float* __restrict__ bhh,
                       unsigned short* __restrict__ wih_bf, unsigned short* __restrict__ whh_bf,
                       float* __restrict__ bias){
  int i = blockIdx.x * 256 + threadIdx.x;
  if (i < 2*2*512*256) wih_bf[i] = f2bf(wih[i]);
  if (i < 2*2*512*128) whh_bf[i] = f2bf(whh[i]);
  if (i < 2*2*512)     bias[i]   = bih[i] + bhh[i];
}

// ---------- embedding gather+concat -> x (m = t*32+b, 256) bf16 ----------
__global__ void k_embed(const int* __restrict__ cid, const int* __restrict__ wid,
                        const float* __restrict__ cemb, const float* __restrict__ wemb,
                        unsigned short* __restrict__ x){
  int m = blockIdx.x, d = threadIdx.x;      // 128 threads
  int t = m >> 5, b = m & 31;
  int c = cid[b*TT + t], w = wid[b*TT + t];
  x[(size_t)m*256 + d]       = f2bf(cemb[c*128 + d]);
  x[(size_t)m*256 + 128 + d] = f2bf(wemb[(size_t)w*128 + d]);
}

// ---------- input GEMM: pre = x @ wih^T + bias, stored in MFMA C-fragment order ----------
// page(dir,t,half,w) = ((dir*TT+t)*2+half)*8+w, 1024 bf16 elems/page: [lane][g][r]
__global__ __launch_bounds__(256) void k_gemm_pre(const unsigned short* __restrict__ x,
                        const unsigned short* __restrict__ wih_bf,   // layer base (1024,256)
                        const float* __restrict__ bias,              // layer base (1024)
                        unsigned short* __restrict__ pre){
  int lane = threadIdx.x & 63, wv = threadIdx.x >> 6;
  int m0 = blockIdx.x * 64 + wv * 16;
  int r16 = lane & 15, q4 = lane >> 4;
  const unsigned short* arow = x + (size_t)(m0 + r16)*256 + q4*8;
  short8 a[8];
  #pragma unroll
  for (int ks = 0; ks < 8; ++ks) a[ks] = *(const short8*)(arow + ks*32);
  int t = m0 >> 5, half = (m0 >> 4) & 1;
  #pragma unroll
  for (int sub = 0; sub < 4; ++sub){
    int n0 = blockIdx.y * 64 + sub * 16;
    const unsigned short* brow = wih_bf + (size_t)(n0 + r16)*256 + q4*8;
    f32x4 acc = {0.f,0.f,0.f,0.f};
    #pragma unroll
    for (int ks = 0; ks < 8; ++ks){
      short8 bfr = *(const short8*)(brow + ks*32);
      acc = __builtin_amdgcn_mfma_f32_16x16x32_bf16(a[ks], bfr, acc, 0, 0, 0);
    }
    float bs = bias[n0 + r16];
    int dir = n0 >> 9, rem = n0 & 511, g = rem >> 7, w = (rem >> 4) & 7;
    size_t base = (((((size_t)(dir*TT + t)*2 + half)*8 + w)*64 + lane)*4 + (size_t)g)*4;
    us4 st;
    st[0] = f2bf(acc[0] + bs); st[1] = f2bf(acc[1] + bs);
    st[2] = f2bf(acc[2] + bs); st[3] = f2bf(acc[3] + bs);
    *(us4*)(pre + base) = st;
  }
}

// ---------- recurrent LSTM scan: 4 blocks = {dir}x{batch half}, 8 waves each ----------
__global__ __launch_bounds__(512) void k_lstm(const unsigned short* __restrict__ pre,
                                              const unsigned short* __restrict__ whh_bf, // layer base (2,512,128)
                                              unsigned short* __restrict__ y){
  int dir = blockIdx.x >> 1, half = blockIdx.x & 1;
  int tid = threadIdx.x, lane = tid & 63, w = tid >> 6;
  int r16 = lane & 15, q4 = lane >> 4;
  __shared__ __align__(16) unsigned char hsh[4096];   // h tile [16 batch][128 h] bf16, XOR-swizzled
  *(unsigned long long*)(hsh + tid*8) = 0ull;

  // Whh B-fragments, constant across steps: B[k][n] = whh[n][k]
  short8 bfrag[4][4];
  const unsigned short* whhd = whh_bf + (size_t)dir*512*128;
  #pragma unroll
  for (int g = 0; g < 4; ++g)
    #pragma unroll
    for (int ks = 0; ks < 4; ++ks)
      bfrag[g][ks] = *(const short8*)(whhd + (size_t)(g*128 + w*16 + r16)*128 + ks*32 + q4*8);

  const size_t pb0 = ((size_t)dir*TT*16 + half*8 + w)*1024 + (size_t)lane*16;
  #define PLOAD(t,which) (((const us8*)(pre + pb0 + (size_t)(t)*16*1024))[(which)])
  int t0 = dir ? TT-1 : 0;
  int t1 = dir ? TT-2 : 1;
  us8 cp0 = PLOAD(t0,0), cp1 = PLOAD(t0,1);
  us8 nA0 = PLOAD(t1,0), nA1 = PLOAD(t1,1);
  us8 nB0 = nA0, nB1 = nA1;
  float c[4] = {0.f,0.f,0.f,0.f};
  unsigned short hprev[4] = {0,0,0,0};
  int tprev = 0;
  const float L2E = 1.4426950408889634f;
  __syncthreads();

  for (int step = 0; step < TT; ++step){
    int t = dir ? (TT-1-step) : step;
    if (step){   // deferred global h store from previous step (hidden under this step)
      #pragma unroll
      for (int r = 0; r < 4; ++r)
        y[((size_t)tprev*BB + half*16 + q4*4 + r)*256 + dir*128 + w*16 + r16] = hprev[r];
    }
    if (step < TT-2){   // prefetch pre 2 steps ahead
      int tn = dir ? (TT-3-step) : (step+2);
      nB0 = PLOAD(tn,0); nB1 = PLOAD(tn,1);
    }
    // A fragments = h_{t-1} from swizzled LDS
    short8 a[4];
    #pragma unroll
    for (int ks = 0; ks < 4; ++ks)
      a[ks] = *(const short8*)(hsh + r16*256 + ((ks*64 + q4*16) ^ ((r16 & 7) << 4)));
    f32x4 acc[4];
    #pragma unroll
    for (int g = 0; g < 4; ++g){
      f32x4 z = {0.f,0.f,0.f,0.f};
      #pragma unroll
      for (int ks = 0; ks < 4; ++ks)
        z = __builtin_amdgcn_mfma_f32_16x16x32_bf16(a[ks], bfrag[g][ks], z, 0, 0, 0);
      acc[g] = z;
    }
    block_sync();   // all h reads done before overwrite
    unsigned short hout[4];
    #pragma unroll
    for (int r = 0; r < 4; ++r){
      float ai = acc[0][r] + bf2f(cp0[r]);
      float af = acc[1][r] + bf2f(cp0[4+r]);
      float ag = acc[2][r] + bf2f(cp1[r]);
      float ao = acc[3][r] + bf2f(cp1[4+r]);
      float si = __builtin_amdgcn_rcpf(1.f + __builtin_amdgcn_exp2f(-ai*L2E));
      float sf = __builtin_amdgcn_rcpf(1.f + __builtin_amdgcn_exp2f(-af*L2E));
      float tg = 1.f - 2.f*__builtin_amdgcn_rcpf(1.f + __builtin_amdgcn_exp2f(ag*(2.f*L2E)));
      float so = __builtin_amdgcn_rcpf(1.f + __builtin_amdgcn_exp2f(-ao*L2E));
      float cc = sf*c[r] + si*tg;
      c[r] = cc;
      float th = 1.f - 2.f*__builtin_amdgcn_rcpf(1.f + __builtin_amdgcn_exp2f(cc*(2.f*L2E)));
      hout[r] = f2bf(so*th);
    }
    int h0 = w*16 + r16;
    #pragma unroll
    for (int r = 0; r < 4; ++r){
      int bl = q4*4 + r;
      *(unsigned short*)(hsh + bl*256 + ((h0*2) ^ ((bl & 7) << 4))) = hout[r];
      hprev[r] = hout[r];
    }
    tprev = t;
    block_sync();   // writes visible before next step's reads
    cp0 = nA0; cp1 = nA1; nA0 = nB0; nA1 = nB1;
  }
  #pragma unroll
  for (int r = 0; r < 4; ++r)
    y[((size_t)tprev*BB + half*16 + q4*4 + r)*256 + dir*128 + w*16 + r16] = hprev[r];
}

// ---------- emissions: em[m][k] = y[m]·fcw[k] + fcb[k] ----------
__global__ void k_emis(const unsigned short* __restrict__ y, const float* __restrict__ fcw,
                       const float* __restrict__ fcb, float* __restrict__ em){
  int idx = blockIdx.x*256 + threadIdx.x;
  if (idx >= TT*BB*KK) return;
  int m = idx / KK, k = idx - m*KK;
  const us8* yr = (const us8*)(y + (size_t)m*256);
  const float* wr = fcw + k*256;
  float s = fcb[k];
  #pragma unroll 4
  for (int cb = 0; cb < 32; ++cb){
    us8 v = yr[cb];
    #pragma unroll
    for (int j = 0; j < 8; ++j) s += bf2f(v[j]) * wr[cb*8 + j];
  }
  em[(size_t)m*16 + k] = s;
}

// ---------- CRF NLL: numerator (parallel) + forward algorithm (sequential T) ----------
__global__ __launch_bounds__(512) void k_crf(const float* __restrict__ em, const int* __restrict__ tags,
                    const int* __restrict__ mask, const float* __restrict__ trans,
                    const float* __restrict__ startt, const float* __restrict__ endt,
                    float* __restrict__ out){
  __shared__ float sh_tr[15][16];
  __shared__ float sh_s[16], sh_e[16];
  __shared__ float alpha[32][16];
  __shared__ float red[8];
  __shared__ float dens[32];
  __shared__ int seqend[32];
  int tid = threadIdx.x;
  if (tid < 225) sh_tr[tid/15][tid%15] = trans[tid];
  if (tid < 15){ sh_s[tid] = startt[tid]; sh_e[tid] = endt[tid]; }
  if (tid < 32){
    int cnt = 0;
    for (int t = 0; t < TT; ++t) cnt += (mask[tid*TT + t] != 0) ? 1 : 0;
    seqend[tid] = cnt - 1;
  }
  __syncthreads();
  const float L2E = 1.4426950408889634f, LN2 = 0.6931471805599453f;
  // ---- numerator (gold path score), fully parallel over (b,t)
  float num = 0.f;
  for (int i = tid; i < BB*TT; i += 512){
    int b = i >> 9, t = i & (TT-1);
    int tg = tags[b*TT + t];
    if (t == 0){
      num += sh_s[tg] + em[b*16 + tg];
    } else if (mask[b*TT + t] != 0){
      int tp = tags[b*TT + t - 1];
      num += sh_tr[tp][tg] + em[((size_t)t*BB + b)*16 + tg];
    }
  }
  if (tid < 32) num += sh_e[tags[tid*TT + seqend[tid]]];
  #pragma unroll
  for (int off = 32; off > 0; off >>= 1) num += __shfl_down(num, off, 64);
  if ((tid & 63) == 0) red[tid >> 6] = num;
  // ---- denominator: forward algorithm, alpha (B,K) in LDS
  int b = tid / 15, j = tid - b*15;
  bool act = tid < 480;
  if (act) alpha[b][j] = sh_s[j] + em[b*16 + j];
  __syncthreads();
  for (int t = 1; t < TT; ++t){
    float nxt = 0.f; bool mk = false;
    if (act){
      mk = mask[b*TT + t] != 0;
      float mx = -3.0e38f;
      #pragma unroll
      for (int i2 = 0; i2 < 15; ++i2) mx = fmaxf(mx, alpha[b][i2] + sh_tr[i2][j]);
      float s = 0.f;
      #pragma unroll
      for (int i2 = 0; i2 < 15; ++i2)
        s += __builtin_amdgcn_exp2f((alpha[b][i2] + sh_tr[i2][j] - mx)*L2E);
      nxt = mx + __builtin_amdgcn_logf(s)*LN2 + em[((size_t)t*BB + b)*16 + j];
    }
    __syncthreads();
    if (act && mk) alpha[b][j] = nxt;
    __syncthreads();
  }
  if (tid < 32){
    float mx = -3.0e38f;
    #pragma unroll
    for (int j2 = 0; j2 < 15; ++j2) mx = fmaxf(mx, alpha[tid][j2] + sh_e[j2]);
    float s = 0.f;
    #pragma unroll
    for (int j2 = 0; j2 < 15; ++j2)
      s += __builtin_amdgcn_exp2f((alpha[tid][j2] + sh_e[j2] - mx)*L2E);
    dens[tid] = mx + __builtin_amdgcn_logf(s)*LN2;
  }
  __syncthreads();
  if (tid == 0){
    float numtot = 0.f;
    #pragma unroll
    for (int i = 0; i < 8; ++i) numtot += red[i];
    float dentot = 0.f;
    for (int i = 0; i < 32; ++i) dentot += dens[i];
    out[0] = dentot - numtot;   // = -(num - den).sum()
  }
}

extern "C" void kernel_launch(void* const* d_in, const int* in_sizes, int n_in,
                              void* d_out, int out_size, void* d_ws, size_t ws_size,
                              hipStream_t stream){
  const int*   cid  = (const int*)d_in[0];
  const int*   wid  = (const int*)d_in[1];
  const int*   tags = (const int*)d_in[2];
  const int*   mask = (const int*)d_in[3];
  const float* cemb = (const float*)d_in[4];
  const float* wemb = (const float*)d_in[5];
  const float* wih  = (const float*)d_in[6];
  const float* whh  = (const float*)d_in[7];
  const float* bih  = (const float*)d_in[8];
  const float* bhh  = (const float*)d_in[9];
  const float* fcw  = (const float*)d_in[10];
  const float* fcb  = (const float*)d_in[11];
  const float* trans= (const float*)d_in[12];
  const float* st   = (const float*)d_in[13];
  const float* en   = (const float*)d_in[14];

  char* ws = (char*)d_ws;
  size_t off = 0;
  auto alloc = [&](size_t bytes){ size_t o = off; off += (bytes + 255) & ~(size_t)255; return o; };
  unsigned short* wih_bf = (unsigned short*)(ws + alloc((size_t)2*2*512*256*2));
  unsigned short* whh_bf = (unsigned short*)(ws + alloc((size_t)2*2*512*128*2));
  float*          bias   = (float*)         (ws + alloc((size_t)2*2*512*4));
  unsigned short* x0     = (unsigned short*)(ws + alloc((size_t)TT*BB*256*2));
  unsigned short* x1     = (unsigned short*)(ws + alloc((size_t)TT*BB*256*2));
  unsigned short* pre    = (unsigned short*)(ws + alloc((size_t)2*TT*BB*512*2));
  float*          em     = (float*)         (ws + alloc((size_t)TT*BB*16*4));

  k_prep<<<2048, 256, 0, stream>>>(wih, whh, bih, bhh, wih_bf, whh_bf, bias);
  k_embed<<<TT*BB, 128, 0, stream>>>(cid, wid, cemb, wemb, x0);
  for (int l = 0; l < 2; ++l){
    const unsigned short* xin = l ? x1 : x0;
    unsigned short* yout = l ? x0 : x1;
    k_gemm_pre<<<dim3(256,16), 256, 0, stream>>>(xin, wih_bf + (size_t)l*2*512*256,
                                                 bias + (size_t)l*1024, pre);
    k_lstm<<<4, 512, 0, stream>>>(pre, whh_bf + (size_t)l*2*512*128, yout);
  }
  k_emis<<<(TT*BB*KK + 255)/256, 256, 0, stream>>>(x0, fcw, fcb, em);
  k_crf<<<1, 512, 0, stream>>>(em, tags, mask, trans, st, en, (float*)d_out);
}

// Round 2
// 1544.433 us; speedup vs baseline: 1.0840x; 1.0840x over previous
//
#include <hip/hip_runtime.h>

#define TT 512
#define BB 32
#define KK 15
#define DPF 6   // LDS ring prefetch depth (steps)

typedef __attribute__((ext_vector_type(8))) short short8;
typedef __attribute__((ext_vector_type(4))) float f32x4;
typedef __attribute__((ext_vector_type(8))) unsigned short us8;
typedef __attribute__((ext_vector_type(4))) unsigned short us4;

__device__ __forceinline__ float bf2f(unsigned short u){
  union { unsigned int i; float f; } v; v.i = ((unsigned int)u) << 16; return v.f;
}
__device__ __forceinline__ unsigned short f2bf(float f){
  union { float f; unsigned int i; } v; v.f = f;
  return (unsigned short)((v.i + 0x7fffu + ((v.i >> 16) & 1u)) >> 16);
}

// ---------- prep: f32 -> bf16 weights, fused bias ----------
__global__ void k_prep(const float* __restrict__ wih, const float* __restrict__ whh,
                       const float* __restrict__ bih, const float* __restrict__ bhh,
                       unsigned short* __restrict__ wih_bf, unsigned short* __restrict__ whh_bf,
                       float* __restrict__ bias){
  int i = blockIdx.x * 256 + threadIdx.x;
  if (i < 2*2*512*256) wih_bf[i] = f2bf(wih[i]);
  if (i < 2*2*512*128) whh_bf[i] = f2bf(whh[i]);
  if (i < 2*2*512)     bias[i]   = bih[i] + bhh[i];
}

// ---------- embedding gather+concat -> x (m = t*32+b, 256) bf16 ----------
__global__ void k_embed(const int* __restrict__ cid, const int* __restrict__ wid,
                        const float* __restrict__ cemb, const float* __restrict__ wemb,
                        unsigned short* __restrict__ x){
  int m = blockIdx.x, d = threadIdx.x;      // 128 threads
  int t = m >> 5, b = m & 31;
  int c = cid[b*TT + t], w = wid[b*TT + t];
  x[(size_t)m*256 + d]       = f2bf(cemb[c*128 + d]);
  x[(size_t)m*256 + 128 + d] = f2bf(wemb[(size_t)w*128 + d]);
}

// ---------- input GEMM: pre = x @ wih^T + bias, stored per page as [which(2)][lane(64)][8 elems]
// page(dir,t,half,w) = ((dir*TT+t)*2+half)*8+w, 1024 bf16 elems (2 KB) per page
__global__ __launch_bounds__(256) void k_gemm_pre(const unsigned short* __restrict__ x,
                        const unsigned short* __restrict__ wih_bf,   // layer base (1024,256)
                        const float* __restrict__ bias,              // layer base (1024)
                        unsigned short* __restrict__ pre){
  int lane = threadIdx.x & 63, wv = threadIdx.x >> 6;
  int m0 = blockIdx.x * 64 + wv * 16;
  int r16 = lane & 15, q4 = lane >> 4;
  const unsigned short* arow = x + (size_t)(m0 + r16)*256 + q4*8;
  short8 a[8];
  #pragma unroll
  for (int ks = 0; ks < 8; ++ks) a[ks] = *(const short8*)(arow + ks*32);
  int t = m0 >> 5, half = (m0 >> 4) & 1;
  #pragma unroll
  for (int sub = 0; sub < 4; ++sub){
    int n0 = blockIdx.y * 64 + sub * 16;
    const unsigned short* brow = wih_bf + (size_t)(n0 + r16)*256 + q4*8;
    f32x4 acc = {0.f,0.f,0.f,0.f};
    #pragma unroll
    for (int ks = 0; ks < 8; ++ks){
      short8 bfr = *(const short8*)(brow + ks*32);
      acc = __builtin_amdgcn_mfma_f32_16x16x32_bf16(a[ks], bfr, acc, 0, 0, 0);
    }
    float bs = bias[n0 + r16];
    int dir = n0 >> 9, rem = n0 & 511, g = rem >> 7, w = (rem >> 4) & 7;
    size_t page = (((size_t)(dir*TT + t)*2 + half)*8 + w);
    size_t base = page*1024 + (size_t)(g>>1)*512 + (size_t)lane*8 + (g&1)*4;
    us4 st;
    st[0] = f2bf(acc[0] + bs); st[1] = f2bf(acc[1] + bs);
    st[2] = f2bf(acc[2] + bs); st[3] = f2bf(acc[3] + bs);
    *(us4*)(pre + base) = st;
  }
}

// ---------- recurrent LSTM scan: 4 blocks = {dir}x{batch half}, 8 waves each ----------
// pre staged through a DPF-deep LDS ring via global_load_lds; counted vmcnt; h double-buffered
__global__ __launch_bounds__(512) void k_lstm(const unsigned short* __restrict__ pre,
                                              const unsigned short* __restrict__ whh_bf, // layer base (2,512,128)
                                              unsigned short* __restrict__ y){
  int dir = blockIdx.x >> 1, half = blockIdx.x & 1;
  int tid = threadIdx.x, lane = tid & 63, w = tid >> 6;
  int r16 = lane & 15, q4 = lane >> 4;
  __shared__ __align__(16) unsigned char ring[DPF*16384];   // DPF slots x (8 waves x 2KB)
  __shared__ __align__(16) unsigned char hbuf[2][4096];     // h tile [16 batch][128 h] bf16, XOR-swizzled
  *(unsigned long long*)(hbuf[0] + tid*8) = 0ull;
  *(unsigned long long*)(hbuf[1] + tid*8) = 0ull;

  // Whh B-fragments, constant across steps
  short8 bfrag[4][4];
  const unsigned short* whhd = whh_bf + (size_t)dir*512*128;
  #pragma unroll
  for (int g = 0; g < 4; ++g)
    #pragma unroll
    for (int ks = 0; ks < 4; ++ks)
      bfrag[g][ks] = *(const short8*)(whhd + (size_t)(g*128 + w*16 + r16)*128 + ks*32 + q4*8);

  const char* preb = (const char*)pre;
  auto issue = [&](int t, int slot){
    size_t pageb = ((((size_t)dir*TT + t)*2 + half)*8 + w)*2048;
    #pragma unroll
    for (int which = 0; which < 2; ++which){
      __builtin_amdgcn_global_load_lds(
        (const __attribute__((address_space(1))) unsigned int*)(preb + pageb + which*1024 + (size_t)lane*16),
        (__attribute__((address_space(3))) unsigned int*)(ring + slot*16384 + w*2048 + which*1024),
        16, 0, 0);
    }
  };
  #pragma unroll
  for (int s = 0; s < DPF; ++s) issue(dir ? TT-1-s : s, s);
  __syncthreads();   // drains prologue loads (vmcnt 0) + hbuf zero-init visible

  float c[4] = {0.f,0.f,0.f,0.f};
  unsigned short hprev[4] = {0,0,0,0};
  int tprev = 0, slot = 0, p = 0;
  const float L2E = 1.4426950408889634f;

  for (int step = 0; step < TT; ++step){
    int t = dir ? (TT-1-step) : step;
    if (step){   // deferred global h store from previous step
      #pragma unroll
      for (int r = 0; r < 4; ++r)
        y[((size_t)tprev*BB + half*16 + q4*4 + r)*256 + dir*128 + w*16 + r16] = hprev[r];
    }
    // slot's 2 loads were issued DPF steps ago; ops issued since = 5*6+4 = 34 >= 28 -> complete
    asm volatile("s_waitcnt vmcnt(28)" ::: "memory");
    const us8* pp = (const us8*)(ring + slot*16384 + w*2048);
    us8 cp0 = pp[lane];
    us8 cp1 = pp[64 + lane];
    short8 a[4];
    #pragma unroll
    for (int ks = 0; ks < 4; ++ks)
      a[ks] = *(const short8*)(hbuf[p] + r16*256 + ((ks*64 + q4*16) ^ ((r16 & 7) << 4)));
    f32x4 acc[4];
    #pragma unroll
    for (int g = 0; g < 4; ++g){
      f32x4 z = {0.f,0.f,0.f,0.f};
      #pragma unroll
      for (int ks = 0; ks < 4; ++ks)
        z = __builtin_amdgcn_mfma_f32_16x16x32_bf16(a[ks], bfrag[g][ks], z, 0, 0, 0);
      acc[g] = z;
    }
    // all ds_reads of this slot must retire before we overwrite it with the next prefetch
    asm volatile("s_waitcnt lgkmcnt(0)" ::: "memory");
    __builtin_amdgcn_sched_barrier(0);
    { int sn = step + DPF; int tn = sn < TT ? (dir ? TT-1-sn : sn) : t; issue(tn, slot); }
    unsigned short hout[4];
    #pragma unroll
    for (int r = 0; r < 4; ++r){
      float ai = acc[0][r] + bf2f(cp0[r]);
      float af = acc[1][r] + bf2f(cp0[4+r]);
      float ag = acc[2][r] + bf2f(cp1[r]);
      float ao = acc[3][r] + bf2f(cp1[4+r]);
      float si = __builtin_amdgcn_rcpf(1.f + __builtin_amdgcn_exp2f(-ai*L2E));
      float sf = __builtin_amdgcn_rcpf(1.f + __builtin_amdgcn_exp2f(-af*L2E));
      float tg = 1.f - 2.f*__builtin_amdgcn_rcpf(1.f + __builtin_amdgcn_exp2f(ag*(2.f*L2E)));
      float so = __builtin_amdgcn_rcpf(1.f + __builtin_amdgcn_exp2f(-ao*L2E));
      float cc = sf*c[r] + si*tg;
      c[r] = cc;
      float th = 1.f - 2.f*__builtin_amdgcn_rcpf(1.f + __builtin_amdgcn_exp2f(cc*(2.f*L2E)));
      hout[r] = f2bf(so*th);
    }
    int h0 = w*16 + r16;
    #pragma unroll
    for (int r = 0; r < 4; ++r){
      int bl = q4*4 + r;
      *(unsigned short*)(hbuf[p^1] + bl*256 + ((h0*2) ^ ((bl & 7) << 4))) = hout[r];
      hprev[r] = hout[r];
    }
    tprev = t;
    asm volatile("s_waitcnt lgkmcnt(0)" ::: "memory");   // h writes committed
    __builtin_amdgcn_s_barrier();                        // raw: does NOT drain vmcnt
    p ^= 1; slot = (slot + 1 == DPF) ? 0 : slot + 1;
  }
  #pragma unroll
  for (int r = 0; r < 4; ++r)
    y[((size_t)tprev*BB + half*16 + q4*4 + r)*256 + dir*128 + w*16 + r16] = hprev[r];
}

// ---------- emissions: em[m][k] = y[m]·fcw[k] + fcb[k] ----------
__global__ void k_emis(const unsigned short* __restrict__ y, const float* __restrict__ fcw,
                       const float* __restrict__ fcb, float* __restrict__ em){
  int idx = blockIdx.x*256 + threadIdx.x;
  if (idx >= TT*BB*KK) return;
  int m = idx / KK, k = idx - m*KK;
  const us8* yr = (const us8*)(y + (size_t)m*256);
  const float* wr = fcw + k*256;
  float s = fcb[k];
  #pragma unroll 4
  for (int cb = 0; cb < 32; ++cb){
    us8 v = yr[cb];
    #pragma unroll
    for (int j = 0; j < 8; ++j) s += bf2f(v[j]) * wr[cb*8 + j];
  }
  em[(size_t)m*16 + k] = s;
}

// ---------- CRF NLL: numerator (parallel) + barrier-free forward algorithm ----------
// denominator: lane j of each 16-lane group holds alpha_j for one batch; exchange via ds_bpermute
__global__ __launch_bounds__(512) void k_crf(const float* __restrict__ em, const int* __restrict__ tags,
                    const int* __restrict__ mask, const float* __restrict__ trans,
                    const float* __restrict__ startt, const float* __restrict__ endt,
                    float* __restrict__ out){
  __shared__ float sh_tr[15][16];
  __shared__ float sh_s[16], sh_e[16];
  __shared__ float red[8];
  __shared__ float dens[32];
  __shared__ int seqend[32];
  int tid = threadIdx.x, lane = tid & 63, wv = tid >> 6;
  if (tid < 225) sh_tr[tid/15][tid%15] = trans[tid];
  if (tid < 15){ sh_s[tid] = startt[tid]; sh_e[tid] = endt[tid]; }
  {
    int b2 = tid >> 4, ch = tid & 15;
    int cnt = 0;
    #pragma unroll 4
    for (int t2 = 0; t2 < 32; ++t2) cnt += (mask[b2*TT + ch*32 + t2] != 0) ? 1 : 0;
    #pragma unroll
    for (int off = 8; off; off >>= 1) cnt += __shfl_down(cnt, off, 16);
    if (ch == 0) seqend[b2] = cnt - 1;
  }
  __syncthreads();
  const float L2E = 1.4426950408889634f, LN2 = 0.6931471805599453f;
  // ---- numerator (gold path score), parallel over (b,t)
  float num = 0.f;
  #pragma unroll 4
  for (int i = tid; i < BB*TT; i += 512){
    int b2 = i >> 9, t = i & (TT-1);
    int tg = tags[b2*TT + t];
    if (t == 0){
      num += sh_s[tg] + em[b2*16 + tg];
    } else if (mask[b2*TT + t] != 0){
      int tp = tags[b2*TT + t - 1];
      num += sh_tr[tp][tg] + em[((size_t)t*BB + b2)*16 + tg];
    }
  }
  if (tid < 32) num += sh_e[tags[tid*TT + seqend[tid]]];
  #pragma unroll
  for (int off = 32; off; off >>= 1) num += __shfl_down(num, off, 64);
  if ((tid & 63) == 0) red[wv] = num;
  // ---- denominator: register alpha, no barriers
  int g = lane >> 4, j = lane & 15;
  int b = wv*4 + g;
  int jj = j < 15 ? j : 14;
  float tr_j[15];
  #pragma unroll
  for (int i = 0; i < 15; ++i) tr_j[i] = trans[i*15 + jj];
  float alpha = sh_s[jj] + em[b*16 + jj];
  int pbase = (lane & 48) << 2;
  auto body = [&](float em_t, int mk){
    float v[15];
    int ai = __float_as_int(alpha);
    #pragma unroll
    for (int i = 0; i < 15; ++i)
      v[i] = __int_as_float(__builtin_amdgcn_ds_bpermute(pbase + i*4, ai)) + tr_j[i];
    float m01 = fmaxf(v[0],v[1]), m23 = fmaxf(v[2],v[3]);
    float m45 = fmaxf(v[4],v[5]), m67 = fmaxf(v[6],v[7]);
    float m89 = fmaxf(v[8],v[9]), mab = fmaxf(v[10],v[11]), mcd = fmaxf(v[12],v[13]);
    float mx = fmaxf(fmaxf(fmaxf(m01,m23), fmaxf(m45,m67)),
                     fmaxf(fmaxf(m89,mab), fmaxf(mcd, v[14])));
    float e[15];
    #pragma unroll
    for (int i = 0; i < 15; ++i) e[i] = __builtin_amdgcn_exp2f((v[i]-mx)*L2E);
    float s = (((e[0]+e[1])+(e[2]+e[3])) + ((e[4]+e[5])+(e[6]+e[7])))
            + (((e[8]+e[9])+(e[10]+e[11])) + ((e[12]+e[13])+e[14]));
    float nxt = mx + __builtin_amdgcn_logf(s)*LN2 + em_t;
    alpha = mk ? nxt : alpha;
  };
  float emA = em[((size_t)1*BB + b)*16 + jj], emB = em[((size_t)2*BB + b)*16 + jj];
  int mkA = mask[b*TT + 1], mkB = mask[b*TT + 2];
  for (int t = 1; t + 1 < TT; t += 2){
    int ta = t+2 < TT ? t+2 : TT-1;
    int tb = t+3 < TT ? t+3 : TT-1;
    float emA2 = em[((size_t)ta*BB + b)*16 + jj];
    float emB2 = em[((size_t)tb*BB + b)*16 + jj];
    int mkA2 = mask[b*TT + ta], mkB2 = mask[b*TT + tb];
    body(emA, mkA);
    body(emB, mkB);
    emA = emA2; emB = emB2; mkA = mkA2; mkB = mkB2;
  }
  body(emA, mkA);   // t = TT-1
  float val = (j < 15) ? alpha + sh_e[j] : -3.0e38f;
  float mx = val;
  #pragma unroll
  for (int off = 8; off; off >>= 1) mx = fmaxf(mx, __shfl_xor(mx, off, 16));
  float ee = (j < 15) ? __builtin_amdgcn_exp2f((val-mx)*L2E) : 0.f;
  #pragma unroll
  for (int off = 8; off; off >>= 1) ee += __shfl_xor(ee, off, 16);
  if (j == 0) dens[b] = mx + __builtin_amdgcn_logf(ee)*LN2;
  __syncthreads();
  if (tid == 0){
    float numtot = 0.f;
    #pragma unroll
    for (int i = 0; i < 8; ++i) numtot += red[i];
    float dentot = 0.f;
    for (int i = 0; i < 32; ++i) dentot += dens[i];
    out[0] = dentot - numtot;   // = -(num - den).sum()
  }
}

extern "C" void kernel_launch(void* const* d_in, const int* in_sizes, int n_in,
                              void* d_out, int out_size, void* d_ws, size_t ws_size,
                              hipStream_t stream){
  const int*   cid  = (const int*)d_in[0];
  const int*   wid  = (const int*)d_in[1];
  const int*   tags = (const int*)d_in[2];
  const int*   mask = (const int*)d_in[3];
  const float* cemb = (const float*)d_in[4];
  const float* wemb = (const float*)d_in[5];
  const float* wih  = (const float*)d_in[6];
  const float* whh  = (const float*)d_in[7];
  const float* bih  = (const float*)d_in[8];
  const float* bhh  = (const float*)d_in[9];
  const float* fcw  = (const float*)d_in[10];
  const float* fcb  = (const float*)d_in[11];
  const float* trans= (const float*)d_in[12];
  const float* st   = (const float*)d_in[13];
  const float* en   = (const float*)d_in[14];

  char* ws = (char*)d_ws;
  size_t off = 0;
  auto alloc = [&](size_t bytes){ size_t o = off; off += (bytes + 255) & ~(size_t)255; return o; };
  unsigned short* wih_bf = (unsigned short*)(ws + alloc((size_t)2*2*512*256*2));
  unsigned short* whh_bf = (unsigned short*)(ws + alloc((size_t)2*2*512*128*2));
  float*          bias   = (float*)         (ws + alloc((size_t)2*2*512*4));
  unsigned short* x0     = (unsigned short*)(ws + alloc((size_t)TT*BB*256*2));
  unsigned short* x1     = (unsigned short*)(ws + alloc((size_t)TT*BB*256*2));
  unsigned short* pre    = (unsigned short*)(ws + alloc((size_t)2*TT*BB*512*2));
  float*          em     = (float*)         (ws + alloc((size_t)TT*BB*16*4));

  k_prep<<<2048, 256, 0, stream>>>(wih, whh, bih, bhh, wih_bf, whh_bf, bias);
  k_embed<<<TT*BB, 128, 0, stream>>>(cid, wid, cemb, wemb, x0);
  for (int l = 0; l < 2; ++l){
    const unsigned short* xin = l ? x1 : x0;
    unsigned short* yout = l ? x0 : x1;
    k_gemm_pre<<<dim3(256,16), 256, 0, stream>>>(xin, wih_bf + (size_t)l*2*512*256,
                                                 bias + (size_t)l*1024, pre);
    k_lstm<<<4, 512, 0, stream>>>(pre, whh_bf + (size_t)l*2*512*128, yout);
  }
  k_emis<<<(TT*BB*KK + 255)/256, 256, 0, stream>>>(x0, fcw, fcb, em);
  k_crf<<<1, 512, 0, stream>>>(em, tags, mask, trans, st, en, (float*)d_out);
}

// Round 3
// 1393.969 us; speedup vs baseline: 1.2010x; 1.1079x over previous
//
#include <hip/hip_runtime.h>

#define TT 512
#define BB 32
#define KK 15
#define DPF 6   // LDS ring prefetch depth (steps)

typedef __attribute__((ext_vector_type(8))) short short8;
typedef __attribute__((ext_vector_type(4))) float f32x4;
typedef __attribute__((ext_vector_type(8))) unsigned short us8;
typedef __attribute__((ext_vector_type(4))) unsigned short us4;

__device__ __forceinline__ float bf2f(unsigned short u){
  union { unsigned int i; float f; } v; v.i = ((unsigned int)u) << 16; return v.f;
}
__device__ __forceinline__ unsigned short f2bf(float f){
  union { float f; unsigned int i; } v; v.f = f;
  return (unsigned short)((v.i + 0x7fffu + ((v.i >> 16) & 1u)) >> 16);
}

// ---------- prep: f32 -> bf16 weights, fused bias ----------
__global__ void k_prep(const float* __restrict__ wih, const float* __restrict__ whh,
                       const float* __restrict__ bih, const float* __restrict__ bhh,
                       unsigned short* __restrict__ wih_bf, unsigned short* __restrict__ whh_bf,
                       float* __restrict__ bias){
  int i = blockIdx.x * 256 + threadIdx.x;
  if (i < 2*2*512*256) wih_bf[i] = f2bf(wih[i]);
  if (i < 2*2*512*128) whh_bf[i] = f2bf(whh[i]);
  if (i < 2*2*512)     bias[i]   = bih[i] + bhh[i];
}

// ---------- embedding gather+concat -> x (m = t*32+b, 256) bf16 ----------
__global__ void k_embed(const int* __restrict__ cid, const int* __restrict__ wid,
                        const float* __restrict__ cemb, const float* __restrict__ wemb,
                        unsigned short* __restrict__ x){
  int m = blockIdx.x, d = threadIdx.x;      // 128 threads
  int t = m >> 5, b = m & 31;
  int c = cid[b*TT + t], w = wid[b*TT + t];
  x[(size_t)m*256 + d]       = f2bf(cemb[c*128 + d]);
  x[(size_t)m*256 + 128 + d] = f2bf(wemb[(size_t)w*128 + d]);
}

// ---------- input GEMM: pre = x @ wih^T + bias ----------
// pre layout: page(dir, t, group=b>>2, w=hcol>>4) of 256 bf16 (512B):
//   elem = (b_lo*16 + hcol_lo)*4 + gate   (b_lo = b&3)
__global__ __launch_bounds__(256) void k_gemm_pre(const unsigned short* __restrict__ x,
                        const unsigned short* __restrict__ wih_bf,   // layer base (1024,256)
                        const float* __restrict__ bias,              // layer base (1024)
                        unsigned short* __restrict__ pre){
  int lane = threadIdx.x & 63, wv = threadIdx.x >> 6;
  int m0 = blockIdx.x * 64 + wv * 16;
  int r16 = lane & 15, q4 = lane >> 4;
  const unsigned short* arow = x + (size_t)(m0 + r16)*256 + q4*8;
  short8 a[8];
  #pragma unroll
  for (int ks = 0; ks < 8; ++ks) a[ks] = *(const short8*)(arow + ks*32);
  int t = m0 >> 5, half = (m0 >> 4) & 1;
  #pragma unroll
  for (int sub = 0; sub < 4; ++sub){
    int n0 = blockIdx.y * 64 + sub * 16;
    const unsigned short* brow = wih_bf + (size_t)(n0 + r16)*256 + q4*8;
    f32x4 acc = {0.f,0.f,0.f,0.f};
    #pragma unroll
    for (int ks = 0; ks < 8; ++ks){
      short8 bfr = *(const short8*)(brow + ks*32);
      acc = __builtin_amdgcn_mfma_f32_16x16x32_bf16(a[ks], bfr, acc, 0, 0, 0);
    }
    float bs = bias[n0 + r16];
    int dir = n0 >> 9, g = (n0 >> 7) & 3, w = (n0 >> 4) & 7;
    int group = half*4 + q4;           // C row = batch_in_16 = q4*4+rr
    size_t pagebase = ((((size_t)dir*TT + t)*8 + group)*8 + w)*256;
    #pragma unroll
    for (int rr = 0; rr < 4; ++rr)
      pre[pagebase + (size_t)((rr*16 + r16)*4 + g)] = f2bf(acc[rr] + bs);
  }
}

// ---------- recurrent LSTM scan: 16 blocks = {dir(2)} x {batch group of 4 (8)} ----------
// Transposed MFMA: A = Whh (regs), B = h (4 valid batch cols). 1 activation per lane
// via ds_bpermute redistribution. pre staged through LDS ring, counted vmcnt.
__global__ __launch_bounds__(512) void k_lstm(const unsigned short* __restrict__ pre,
                                              const unsigned short* __restrict__ whh_bf, // layer base (2,512,128)
                                              unsigned short* __restrict__ y){
  int dir = blockIdx.x >> 3, grp = blockIdx.x & 7;
  int tid = threadIdx.x, lane = tid & 63, w = tid >> 6;
  int r16 = lane & 15, q4 = lane >> 4;
  __shared__ __align__(16) unsigned char ring[DPF*4096];   // DPF slots x (8 waves x 512B)
  __shared__ __align__(16) unsigned char hbuf[2*1024];     // 2 x [4 batch][128 h] bf16, XOR-swizzled
  *(unsigned int*)(hbuf + tid*4) = 0u;

  // Whh fragments as MFMA A-operand (M = gate outputs), constant across steps
  short8 afrag[4][4];
  const unsigned short* whhd = whh_bf + (size_t)dir*512*128;
  #pragma unroll
  for (int g = 0; g < 4; ++g)
    #pragma unroll
    for (int ks = 0; ks < 4; ++ks)
      afrag[g][ks] = *(const short8*)(whhd + (size_t)(g*128 + w*16 + r16)*128 + ks*32 + q4*8);

  const char* preb = (const char*)pre;
  auto issue = [&](int t, int slot){
    if (lane < 32)
      __builtin_amdgcn_global_load_lds(
        (const __attribute__((address_space(1))) unsigned int*)
          (preb + ((((size_t)dir*TT + t)*8 + grp)*8 + w)*512 + (size_t)lane*16),
        (__attribute__((address_space(3))) unsigned int*)(ring + slot*4096 + w*512),
        16, 0, 0);
  };
  #pragma unroll
  for (int s = 0; s < DPF; ++s) issue(dir ? TT-1-s : s, s);
  __syncthreads();   // drains prologue loads + hbuf zero-init visible

  float cst = 0.f;
  unsigned short hprev = 0;
  int tprev = 0, slot = 0, p = 0;
  const float L2E = 1.4426950408889634f;
  const size_t ylane = (size_t)(grp*4 + q4)*256 + dir*128 + w*16 + r16;
  short8 bf[4] = {};   // zeros for invalid batch cols (stay zero)
  bool act4 = (r16 < 4);
  bool c0 = (r16 & 1) != 0, c1 = (r16 & 2) != 0;
  int ba = (((r16 >> 2) << 4) + q4) * 4;   // bpermute source lane*4

  for (int step = 0; step < TT; ++step){
    int t = dir ? (TT-1-step) : step;
    if (step)   // deferred global h store from previous step
      y[(size_t)tprev*8192 + ylane] = hprev;
    // slot's load issued DPF steps ago; 11 vmem ops issued after it -> retired
    asm volatile("s_waitcnt vmcnt(11)" ::: "memory");
    // B-frag: h rows = batch (4 valid), predicated read from swizzled hbuf
    const unsigned char* hb = hbuf + p*1024;
    if (act4){
      #pragma unroll
      for (int ks = 0; ks < 4; ++ks)
        bf[ks] = *(const short8*)(hb + r16*256 + ((ks*64 + q4*16) ^ ((r16 & 3) << 5)));
    }
    f32x4 acc[4];
    #pragma unroll
    for (int g = 0; g < 4; ++g){
      f32x4 z = {0.f,0.f,0.f,0.f};
      #pragma unroll
      for (int ks = 0; ks < 4; ++ks)
        z = __builtin_amdgcn_mfma_f32_16x16x32_bf16(afrag[g][ks], bf[ks], z, 0, 0, 0);
      acc[g] = z;   // D[row=gate-n (q4*4+r)][col=batch (r16<4)]
    }
    // redistribute: target lane l=(b<<4|hcol_lo) pulls acc[g][hcol_lo&3] from lane (hcol_lo>>2)*16+b
    float sel[4];
    #pragma unroll
    for (int g = 0; g < 4; ++g){
      float b0 = __int_as_float(__builtin_amdgcn_ds_bpermute(ba, __float_as_int(acc[g][0])));
      float b1 = __int_as_float(__builtin_amdgcn_ds_bpermute(ba, __float_as_int(acc[g][1])));
      float b2 = __int_as_float(__builtin_amdgcn_ds_bpermute(ba, __float_as_int(acc[g][2])));
      float b3 = __int_as_float(__builtin_amdgcn_ds_bpermute(ba, __float_as_int(acc[g][3])));
      float t01 = c0 ? b1 : b0, t23 = c0 ? b3 : b2;
      sel[g] = c1 ? t23 : t01;
    }
    // pre-activations for this lane's (b,hcol): 4 gates contiguous bf16
    us4 pr = *(const us4*)(ring + slot*4096 + w*512 + lane*8);
    // ring slot fully consumed -> refill with step+DPF
    asm volatile("s_waitcnt lgkmcnt(0)" ::: "memory");
    __builtin_amdgcn_sched_barrier(0);
    { int sn = step + DPF; int tn = sn < TT ? (dir ? TT-1-sn : sn) : t; issue(tn, slot); }
    // single activation per lane
    float ai = sel[0] + bf2f(pr[0]);
    float af = sel[1] + bf2f(pr[1]);
    float ag = sel[2] + bf2f(pr[2]);
    float ao = sel[3] + bf2f(pr[3]);
    float si = __builtin_amdgcn_rcpf(1.f + __builtin_amdgcn_exp2f(-ai*L2E));
    float sf = __builtin_amdgcn_rcpf(1.f + __builtin_amdgcn_exp2f(-af*L2E));
    float tg = 1.f - 2.f*__builtin_amdgcn_rcpf(1.f + __builtin_amdgcn_exp2f(ag*(2.f*L2E)));
    float so = __builtin_amdgcn_rcpf(1.f + __builtin_amdgcn_exp2f(-ao*L2E));
    cst = sf*cst + si*tg;
    float th = 1.f - 2.f*__builtin_amdgcn_rcpf(1.f + __builtin_amdgcn_exp2f(cst*(2.f*L2E)));
    hprev = f2bf(so*th);
    // h write: row = b (=q4), col = w*16+r16, swizzled
    *(unsigned short*)(hbuf + (p^1)*1024 + q4*256 + ((w*32 + r16*2) ^ ((q4 & 3) << 5))) = hprev;
    tprev = t;
    asm volatile("s_waitcnt lgkmcnt(0)" ::: "memory");   // h writes committed
    __builtin_amdgcn_s_barrier();                        // raw: does NOT drain vmcnt
    p ^= 1; slot = (slot + 1 == DPF) ? 0 : slot + 1;
  }
  y[(size_t)tprev*8192 + ylane] = hprev;
}

// ---------- emissions: em[m][k] = y[m]·fcw[k] + fcb[k] ----------
__global__ void k_emis(const unsigned short* __restrict__ y, const float* __restrict__ fcw,
                       const float* __restrict__ fcb, float* __restrict__ em){
  int idx = blockIdx.x*256 + threadIdx.x;
  if (idx >= TT*BB*KK) return;
  int m = idx / KK, k = idx - m*KK;
  const us8* yr = (const us8*)(y + (size_t)m*256);
  const float* wr = fcw + k*256;
  float s = fcb[k];
  #pragma unroll 4
  for (int cb = 0; cb < 32; ++cb){
    us8 v = yr[cb];
    #pragma unroll
    for (int j = 0; j < 8; ++j) s += bf2f(v[j]) * wr[cb*8 + j];
  }
  em[(size_t)m*16 + k] = s;
}

// ---------- CRF NLL: numerator (parallel) + barrier-free forward algorithm ----------
__global__ __launch_bounds__(512) void k_crf(const float* __restrict__ em, const int* __restrict__ tags,
                    const int* __restrict__ mask, const float* __restrict__ trans,
                    const float* __restrict__ startt, const float* __restrict__ endt,
                    float* __restrict__ out){
  __shared__ float sh_tr[15][16];
  __shared__ float sh_s[16], sh_e[16];
  __shared__ float red[8];
  __shared__ float dens[32];
  __shared__ int seqend[32];
  int tid = threadIdx.x, lane = tid & 63, wv = tid >> 6;
  if (tid < 225) sh_tr[tid/15][tid%15] = trans[tid];
  if (tid < 15){ sh_s[tid] = startt[tid]; sh_e[tid] = endt[tid]; }
  {
    int b2 = tid >> 4, ch = tid & 15;
    int cnt = 0;
    #pragma unroll 4
    for (int t2 = 0; t2 < 32; ++t2) cnt += (mask[b2*TT + ch*32 + t2] != 0) ? 1 : 0;
    #pragma unroll
    for (int off = 8; off; off >>= 1) cnt += __shfl_down(cnt, off, 16);
    if (ch == 0) seqend[b2] = cnt - 1;
  }
  __syncthreads();
  const float L2E = 1.4426950408889634f, LN2 = 0.6931471805599453f;
  float num = 0.f;
  #pragma unroll 4
  for (int i = tid; i < BB*TT; i += 512){
    int b2 = i >> 9, t = i & (TT-1);
    int tg = tags[b2*TT + t];
    if (t == 0){
      num += sh_s[tg] + em[b2*16 + tg];
    } else if (mask[b2*TT + t] != 0){
      int tp = tags[b2*TT + t - 1];
      num += sh_tr[tp][tg] + em[((size_t)t*BB + b2)*16 + tg];
    }
  }
  if (tid < 32) num += sh_e[tags[tid*TT + seqend[tid]]];
  #pragma unroll
  for (int off = 32; off; off >>= 1) num += __shfl_down(num, off, 64);
  if ((tid & 63) == 0) red[wv] = num;
  // denominator: register alpha, no barriers
  int g = lane >> 4, j = lane & 15;
  int b = wv*4 + g;
  int jj = j < 15 ? j : 14;
  float tr_j[15];
  #pragma unroll
  for (int i = 0; i < 15; ++i) tr_j[i] = trans[i*15 + jj];
  float alpha = sh_s[jj] + em[b*16 + jj];
  int pbase = (lane & 48) << 2;
  auto body = [&](float em_t, int mk){
    float v[15];
    int ai = __float_as_int(alpha);
    #pragma unroll
    for (int i = 0; i < 15; ++i)
      v[i] = __int_as_float(__builtin_amdgcn_ds_bpermute(pbase + i*4, ai)) + tr_j[i];
    float m01 = fmaxf(v[0],v[1]), m23 = fmaxf(v[2],v[3]);
    float m45 = fmaxf(v[4],v[5]), m67 = fmaxf(v[6],v[7]);
    float m89 = fmaxf(v[8],v[9]), mab = fmaxf(v[10],v[11]), mcd = fmaxf(v[12],v[13]);
    float mx = fmaxf(fmaxf(fmaxf(m01,m23), fmaxf(m45,m67)),
                     fmaxf(fmaxf(m89,mab), fmaxf(mcd, v[14])));
    float e[15];
    #pragma unroll
    for (int i = 0; i < 15; ++i) e[i] = __builtin_amdgcn_exp2f((v[i]-mx)*L2E);
    float s = (((e[0]+e[1])+(e[2]+e[3])) + ((e[4]+e[5])+(e[6]+e[7])))
            + (((e[8]+e[9])+(e[10]+e[11])) + ((e[12]+e[13])+e[14]));
    float nxt = mx + __builtin_amdgcn_logf(s)*LN2 + em_t;
    alpha = mk ? nxt : alpha;
  };
  float emA = em[((size_t)1*BB + b)*16 + jj], emB = em[((size_t)2*BB + b)*16 + jj];
  int mkA = mask[b*TT + 1], mkB = mask[b*TT + 2];
  for (int t = 1; t + 1 < TT; t += 2){
    int ta = t+2 < TT ? t+2 : TT-1;
    int tb = t+3 < TT ? t+3 : TT-1;
    float emA2 = em[((size_t)ta*BB + b)*16 + jj];
    float emB2 = em[((size_t)tb*BB + b)*16 + jj];
    int mkA2 = mask[b*TT + ta], mkB2 = mask[b*TT + tb];
    body(emA, mkA);
    body(emB, mkB);
    emA = emA2; emB = emB2; mkA = mkA2; mkB = mkB2;
  }
  body(emA, mkA);   // t = TT-1
  float val = (j < 15) ? alpha + sh_e[j] : -3.0e38f;
  float mx = val;
  #pragma unroll
  for (int off = 8; off; off >>= 1) mx = fmaxf(mx, __shfl_xor(mx, off, 16));
  float ee = (j < 15) ? __builtin_amdgcn_exp2f((val-mx)*L2E) : 0.f;
  #pragma unroll
  for (int off = 8; off; off >>= 1) ee += __shfl_xor(ee, off, 16);
  if (j == 0) dens[b] = mx + __builtin_amdgcn_logf(ee)*LN2;
  __syncthreads();
  if (tid == 0){
    float numtot = 0.f;
    #pragma unroll
    for (int i = 0; i < 8; ++i) numtot += red[i];
    float dentot = 0.f;
    for (int i = 0; i < 32; ++i) dentot += dens[i];
    out[0] = dentot - numtot;   // = -(num - den).sum()
  }
}

extern "C" void kernel_launch(void* const* d_in, const int* in_sizes, int n_in,
                              void* d_out, int out_size, void* d_ws, size_t ws_size,
                              hipStream_t stream){
  const int*   cid  = (const int*)d_in[0];
  const int*   wid  = (const int*)d_in[1];
  const int*   tags = (const int*)d_in[2];
  const int*   mask = (const int*)d_in[3];
  const float* cemb = (const float*)d_in[4];
  const float* wemb = (const float*)d_in[5];
  const float* wih  = (const float*)d_in[6];
  const float* whh  = (const float*)d_in[7];
  const float* bih  = (const float*)d_in[8];
  const float* bhh  = (const float*)d_in[9];
  const float* fcw  = (const float*)d_in[10];
  const float* fcb  = (const float*)d_in[11];
  const float* trans= (const float*)d_in[12];
  const float* st   = (const float*)d_in[13];
  const float* en   = (const float*)d_in[14];

  char* ws = (char*)d_ws;
  size_t off = 0;
  auto alloc = [&](size_t bytes){ size_t o = off; off += (bytes + 255) & ~(size_t)255; return o; };
  unsigned short* wih_bf = (unsigned short*)(ws + alloc((size_t)2*2*512*256*2));
  unsigned short* whh_bf = (unsigned short*)(ws + alloc((size_t)2*2*512*128*2));
  float*          bias   = (float*)         (ws + alloc((size_t)2*2*512*4));
  unsigned short* x0     = (unsigned short*)(ws + alloc((size_t)TT*BB*256*2));
  unsigned short* x1     = (unsigned short*)(ws + alloc((size_t)TT*BB*256*2));
  unsigned short* pre    = (unsigned short*)(ws + alloc((size_t)2*TT*BB*512*2));
  float*          em     = (float*)         (ws + alloc((size_t)TT*BB*16*4));

  k_prep<<<2048, 256, 0, stream>>>(wih, whh, bih, bhh, wih_bf, whh_bf, bias);
  k_embed<<<TT*BB, 128, 0, stream>>>(cid, wid, cemb, wemb, x0);
  for (int l = 0; l < 2; ++l){
    const unsigned short* xin = l ? x1 : x0;
    unsigned short* yout = l ? x0 : x1;
    k_gemm_pre<<<dim3(256,16), 256, 0, stream>>>(xin, wih_bf + (size_t)l*2*512*256,
                                                 bias + (size_t)l*1024, pre);
    k_lstm<<<16, 512, 0, stream>>>(pre, whh_bf + (size_t)l*2*512*128, yout);
  }
  k_emis<<<(TT*BB*KK + 255)/256, 256, 0, stream>>>(x0, fcw, fcb, em);
  k_crf<<<1, 512, 0, stream>>>(em, tags, mask, trans, st, en, (float*)d_out);
}